// Round 1
// baseline (526.076 us; speedup 1.0000x reference)
//
#include <hip/hip_runtime.h>

#define N_NODES 100000
#define N_EDGES 1600000
#define IN_F 128
#define OUT_F 64

// Kernel 1: support = X @ W  (fp32, vector ALU — no fp32 MFMA on CDNA4).
// Block = 256 threads = 4 rows x 64 cols. Weight (128x64 = 32 KB) staged in LDS.
// Also initializes out[row][col] = bias[col] (scatter kernel runs after, same stream).
__global__ __launch_bounds__(256) void gemm_bias_kernel(
    const float* __restrict__ x, const float* __restrict__ w,
    const float* __restrict__ bias,
    float* __restrict__ support, float* __restrict__ out) {
    __shared__ float w_lds[IN_F * OUT_F];   // 32 KB
    __shared__ float x_lds[4 * IN_F];       // 2 KB

    const int t = threadIdx.x;
    // Stage weight: 8192 floats / 256 threads = 32 each, vectorized as float4.
    {
        const float4* w4 = (const float4*)w;
        float4* wl4 = (float4*)w_lds;
        #pragma unroll
        for (int i = 0; i < 8; ++i) wl4[t + 256 * i] = w4[t + 256 * i];
    }
    // Stage 4 rows of x: 512 floats / 256 threads = 2 each (float2).
    {
        const float2* x2 = (const float2*)(x + (size_t)blockIdx.x * 4 * IN_F);
        ((float2*)x_lds)[t] = x2[t];
    }
    __syncthreads();

    const int r = t >> 6;          // 0..3 local row
    const int col = t & 63;
    const int row = blockIdx.x * 4 + r;   // N_NODES % 4 == 0, always in range

    float acc = 0.f;
    const float* xr = &x_lds[r * IN_F];
    #pragma unroll
    for (int k = 0; k < IN_F; ++k) {
        acc += xr[k] * w_lds[k * OUT_F + col];   // xr[k]: wave-broadcast; w_lds: stride-1
    }
    support[(size_t)row * OUT_F + col] = acc;
    out[(size_t)row * OUT_F + col] = bias[col];
}

// Kernel 2: COO scatter-add. One 64-lane wave per edge (4 edges per 256-block).
__global__ __launch_bounds__(256) void scatter_kernel(
    const float* __restrict__ support,
    const int* __restrict__ erow, const int* __restrict__ ecol,
    const float* __restrict__ evals, float* __restrict__ out) {
    const int e = blockIdx.x * 4 + (threadIdx.x >> 6);
    if (e >= N_EDGES) return;
    const int f = threadIdx.x & 63;
    const int dst = erow[e];   // wave-uniform (broadcast load)
    const int src = ecol[e];
    const float v = evals[e];
    const float g = support[(size_t)src * OUT_F + f] * v;
    atomicAdd(&out[(size_t)dst * OUT_F + f], g);
}

extern "C" void kernel_launch(void* const* d_in, const int* in_sizes, int n_in,
                              void* d_out, int out_size, void* d_ws, size_t ws_size,
                              hipStream_t stream) {
    const float* x     = (const float*)d_in[0];
    const float* w     = (const float*)d_in[1];
    const float* bias  = (const float*)d_in[2];
    const int* erow    = (const int*)d_in[3];
    const int* ecol    = (const int*)d_in[4];
    const float* evals = (const float*)d_in[5];
    float* out = (float*)d_out;
    float* support = (float*)d_ws;   // 100000*64*4 = 25.6 MB

    // GEMM + bias-init: 100000 rows / 4 per block = 25000 blocks.
    gemm_bias_kernel<<<N_NODES / 4, 256, 0, stream>>>(x, w, bias, support, out);

    // Scatter: 1.6M edges / 4 per block = 400000 blocks.
    scatter_kernel<<<N_EDGES / 4, 256, 0, stream>>>(support, erow, ecol, evals, out);
}